// Round 1
// baseline (278.155 us; speedup 1.0000x reference)
//
#include <hip/hip_runtime.h>
#include <math.h>

#define D 256
#define SM 25
#define QS 32        // q/k row stride (elements)
#define WROWS 264    // LDS row stride in bf16 elements (528B, 16B-aligned)
#define NCH 4        // agg supports deg+1 <= 256 (measured max deg ~ 44)

typedef short bf16x8 __attribute__((ext_vector_type(8)));
typedef float f32x4  __attribute__((ext_vector_type(4)));

__device__ __forceinline__ unsigned int bf16rne(float f) {
    unsigned int u = __float_as_uint(f);
    return (u + 0x7fffu + ((u >> 16) & 1u)) >> 16;
}
__device__ __forceinline__ float bl(unsigned int lo16) {   // low bf16 -> f32
    return __uint_as_float(lo16 << 16);
}
__device__ __forceinline__ float bh(unsigned int u) {      // high bf16 -> f32
    return __uint_as_float(u & 0xffff0000u);
}

// ---------------- prep: zero cnt + transpose W to bf16 + bias ----------------
__global__ __launch_bounds__(256) void prep_kernel(
    const float* __restrict__ Wq, const float* __restrict__ bq,
    const float* __restrict__ Wk, const float* __restrict__ bk,
    unsigned short* __restrict__ wt_g,   // [64][256] bf16: col j, k
    float* __restrict__ bias_g,          // [64]
    int* __restrict__ cnt, int N) {
    int gid = blockIdx.x * 256 + threadIdx.x;
    if (gid < N) cnt[gid] = 0;
    if (gid < 64 * 256) {
        int j = gid >> 8, k = gid & 255;
        float w = 0.f;
        if (j < SM) w = Wq[k * SM + j];
        else if (j < 2 * SM) w = Wk[k * SM + (j - SM)];
        wt_g[j * 256 + k] = (unsigned short)bf16rne(w);
    }
    if (gid >= 16384 && gid < 16448) {
        int t = gid - 16384;
        bias_g[t] = (t < SM) ? bq[t] : ((t < 2 * SM) ? bk[t - SM] : 0.f);
    }
}

// ---------------- fused convert + q/k heads (MFMA) + histogram ----------------
__global__ __launch_bounds__(256) void qk_kernel(
    const float* __restrict__ x,
    const unsigned short* __restrict__ wt_g, const float* __restrict__ bias_g,
    const int4* __restrict__ dst4, const int* __restrict__ dste,
    unsigned short* __restrict__ xh,       // [N][256] bf16
    float* __restrict__ qp,                // [N][QS] fp32, cols 25..31 = 0
    float* __restrict__ kp,                // [N][QS] fp32, cols 25..31 = 0
    int* __restrict__ cnt, int N, int E) {
    __shared__ __align__(16) short xs[64 * WROWS];
    __shared__ __align__(16) short wt[64 * WROWS];   // wt[col j][k]
    __shared__ float bias[64];
    int t = threadIdx.x;
    int n0 = blockIdx.x * 64;

    // x rows -> bf16 LDS. thread t: row t>>2, quarter t&3 (64 floats)
    {
        int r = t >> 2, qtr = t & 3;
        int row = n0 + r; if (row >= N) row = N - 1;
        const float4* xr = (const float4*)(x + (size_t)row * D) + qtr * 16;
        short* dst = xs + r * WROWS + qtr * 64;
#pragma unroll
        for (int i = 0; i < 16; ++i) {
            float4 a = xr[i];
            unsigned int w0 = bf16rne(a.x) | (bf16rne(a.y) << 16);
            unsigned int w1 = bf16rne(a.z) | (bf16rne(a.w) << 16);
            *(uint2*)(dst + i * 4) = make_uint2(w0, w1);
        }
    }
    // stage pre-transposed W coalesced: 2048 uint4, 8 per thread
#pragma unroll
    for (int o = 0; o < 8; ++o) {
        int idx = o * 256 + t;
        int j = idx >> 5, k8 = idx & 31;
        *(uint4*)(wt + j * WROWS + k8 * 8) = ((const uint4*)wt_g)[idx];
    }
    if (t < 64) bias[t] = bias_g[t];
    __syncthreads();

    // write xh coalesced (32 uint4 per row)
    for (int o = 0; o < 8; ++o) {
        int idx = o * 256 + t;           // 2048 uint4
        int r = idx >> 5, c = idx & 31;
        int row = n0 + r;
        if (row < N) {
            uint4 v = *(const uint4*)(xs + r * WROWS + c * 8);
            *((uint4*)(xh + (size_t)row * D) + c) = v;
        }
    }

    // MFMA: wave handles 16 nodes x 64 cols (4 tiles), K=256 in 8 steps
    int wid = t >> 6, lane = t & 63;
    int mm = lane & 15, g = lane >> 4;
    f32x4 acc[4];
#pragma unroll
    for (int tt = 0; tt < 4; ++tt) acc[tt] = (f32x4){0.f, 0.f, 0.f, 0.f};
    const short* arow = xs + (wid * 16 + mm) * WROWS + g * 8;
#pragma unroll
    for (int ks = 0; ks < 8; ++ks) {
        bf16x8 af = *(const bf16x8*)(arow + ks * 32);
#pragma unroll
        for (int tt = 0; tt < 4; ++tt) {
            bf16x8 bf = *(const bf16x8*)(wt + (tt * 16 + mm) * WROWS + g * 8 + ks * 32);
            acc[tt] = __builtin_amdgcn_mfma_f32_16x16x32_bf16(af, bf, acc[tt], 0, 0, 0);
        }
    }
    // epilogue: C/D layout col = lane&15 (within tile), row = g*4 + reg
#pragma unroll
    for (int tt = 0; tt < 4; ++tt) {
        int j = tt * 16 + mm;
#pragma unroll
        for (int r = 0; r < 4; ++r) {
            int node = n0 + wid * 16 + g * 4 + r;
            if (node >= N) continue;
            float v = acc[tt][r] + bias[j];
            if (j < SM)           qp[(size_t)node * QS + j] = tanhf(v);
            else if (j < 2 * SM)  kp[(size_t)node * QS + (j - SM)] = v;
            else if (j < 57)      qp[(size_t)node * QS + (j - SM)] = 0.f;   // q pad 25..31
            else                  kp[(size_t)node * QS + (j - 32)] = 0.f;   // k pad 25..31
        }
    }

    // histogram share (cnt zeroed by prep_kernel, stream-ordered before us)
    int gid = blockIdx.x * 256 + t;
    int n4e = E >> 2;
    if (gid < n4e) {
        int4 dd = dst4[gid];
        atomicAdd(&cnt[dd.x], 1);
        atomicAdd(&cnt[dd.y], 1);
        atomicAdd(&cnt[dd.z], 1);
        atomicAdd(&cnt[dd.w], 1);
    }
    if (gid == 0) {
        for (int e = n4e * 4; e < E; ++e) atomicAdd(&cnt[dste[e]], 1);
    }
}

// ---------------- scans ----------------
__global__ __launch_bounds__(256) void scan_a_kernel(const int4* __restrict__ cnt4,
                                                     int* __restrict__ bsum, int n4) {
    __shared__ int wsum[4];
    int t = threadIdx.x;
    int idx = blockIdx.x * 256 + t;
    int s = 0;
    if (idx < n4) { int4 v = cnt4[idx]; s = v.x + v.y + v.z + v.w; }
#pragma unroll
    for (int o = 32; o; o >>= 1) s += __shfl_xor(s, o);
    if ((t & 63) == 0) wsum[t >> 6] = s;
    __syncthreads();
    if (t == 0) bsum[blockIdx.x] = wsum[0] + wsum[1] + wsum[2] + wsum[3];
}

// merged phase B+C: every block shfl-scans the <=64 block sums itself
__global__ __launch_bounds__(256) void scan_c_kernel(const int4* __restrict__ cnt4,
                                                     const int* __restrict__ bsum,
                                                     int* __restrict__ offN,
                                                     int4* __restrict__ off4,
                                                     int4* __restrict__ cursor4,
                                                     int n4, int nblk) {
    __shared__ int wsum[4];
    int t = threadIdx.x;
    int lane = t & 63;
    // block-sum scan (redundant per wave)
    int bv = (lane < nblk) ? bsum[lane] : 0;
    int bincl = bv;
#pragma unroll
    for (int o = 1; o < 64; o <<= 1) {
        int u = __shfl_up(bincl, o);
        if (lane >= o) bincl += u;
    }
    int blockbase = __shfl(bincl - bv, blockIdx.x);
    int total = __shfl(bincl, nblk - 1);
    if (blockIdx.x == 0 && t == 0) *offN = total;
    // per-element scan
    int idx = blockIdx.x * 256 + t;
    int4 v = make_int4(0, 0, 0, 0);
    if (idx < n4) v = cnt4[idx];
    int s0 = v.x, s01 = s0 + v.y, s012 = s01 + v.z, s = s012 + v.w;
    int incl = s;
#pragma unroll
    for (int o = 1; o < 64; o <<= 1) {
        int u = __shfl_up(incl, o);
        if (lane >= o) incl += u;
    }
    if (lane == 63) wsum[t >> 6] = incl;
    __syncthreads();
    int w = t >> 6;
    int wbase = 0;
    for (int i = 0; i < w; ++i) wbase += wsum[i];
    int base = blockbase + wbase + (incl - s);
    if (idx < n4) {
        int4 o4 = make_int4(base, base + s0, base + s01, base + s012);
        off4[idx]    = o4;
        cursor4[idx] = o4;
    }
}

__global__ void scatter_kernel(const int4* __restrict__ src4, const int4* __restrict__ dst4,
                               const int* __restrict__ srce, const int* __restrict__ dste,
                               int* __restrict__ cursor, int* __restrict__ csr_src,
                               int n4e, int E) {
    int e = blockIdx.x * blockDim.x + threadIdx.x;
    if (e >= n4e) return;
    int4 s = src4[e];
    int4 d = dst4[e];
    csr_src[atomicAdd(&cursor[d.x], 1)] = s.x;
    csr_src[atomicAdd(&cursor[d.y], 1)] = s.y;
    csr_src[atomicAdd(&cursor[d.z], 1)] = s.z;
    csr_src[atomicAdd(&cursor[d.w], 1)] = s.w;
    if (e == 0) {
        for (int i = n4e * 4; i < E; ++i)
            csr_src[atomicAdd(&cursor[dste[i]], 1)] = srce[i];
    }
}

// ---------------- per-node score + softmax + weighted gather ----------------
// One wave per node (4/block). Scores: lane i = edge i (self loop at i=0).
// Gather: unrolled x8 with independent loads for MLP; lane t owns 8B of row.
__global__ __launch_bounds__(256) void agg_kernel(
        const uint2* __restrict__ xh2, const float* __restrict__ qp,
        const float* __restrict__ kp, const int* __restrict__ off,
        const int* __restrict__ csr_src, float4* __restrict__ out4, int N) {
    int lane = threadIdx.x & 63;
    int v = blockIdx.x * 4 + (threadIdx.x >> 6);
    if (v >= N) return;
    int lo = off[v];
    int deg1 = off[v + 1] - lo + 1;           // + self loop
    const float4* kd4 = (const float4*)(kp + (size_t)v * QS);
    // cols 25..31 of qp/kp are zero-padded, so a 28-element dot == 25-elem dot
    float4 kd[7];
#pragma unroll
    for (int j = 0; j < 7; ++j) kd[j] = kd4[j];

    float wv[NCH]; int sv[NCH];
    float m = -INFINITY;
#pragma unroll
    for (int c = 0; c < NCH; ++c) {
        int i = c * 64 + lane;
        float wcur = -INFINITY; int s = v;
        if (c * 64 < deg1 && i < deg1) {
            if (i > 0) s = csr_src[lo + i - 1];
            const float4* q4 = (const float4*)(qp + (size_t)s * QS);
            float acc = 0.f;
#pragma unroll
            for (int j = 0; j < 7; ++j) {
                float4 a = q4[j];
                acc += a.x*kd[j].x + a.y*kd[j].y + a.z*kd[j].z + a.w*kd[j].w;
            }
            wcur = acc * 0.2f;                 // 1/sqrt(25)
        }
        wv[c] = wcur; sv[c] = s;
        m = fmaxf(m, wcur);
    }
#pragma unroll
    for (int o = 32; o; o >>= 1) m = fmaxf(m, __shfl_xor(m, o));
    float ssum = 0.f;
#pragma unroll
    for (int c = 0; c < NCH; ++c) {
        float e = (wv[c] == -INFINITY) ? 0.f : __expf(wv[c] - m);
        wv[c] = e;
        ssum += e;
    }
#pragma unroll
    for (int o = 32; o; o >>= 1) ssum += __shfl_xor(ssum, o);
    float inv = 1.f / ssum;

    const uint2* xb = xh2 + lane;             // lane-owned 8B column of each row
    float4 acc = make_float4(0.f, 0.f, 0.f, 0.f);
#pragma unroll
    for (int c = 0; c < NCH; ++c) {
        if (c * 64 >= deg1) break;
        int cnt = deg1 - c * 64; if (cnt > 64) cnt = 64;
        int j = 0;
        // 8-deep independent-load batches: cover random-gather latency with MLP
        for (; j + 8 <= cnt; j += 8) {
            float a0 = __shfl(wv[c], j);     int s0 = __shfl(sv[c], j);
            float a1 = __shfl(wv[c], j + 1); int s1 = __shfl(sv[c], j + 1);
            float a2 = __shfl(wv[c], j + 2); int s2 = __shfl(sv[c], j + 2);
            float a3 = __shfl(wv[c], j + 3); int s3 = __shfl(sv[c], j + 3);
            float a4 = __shfl(wv[c], j + 4); int s4 = __shfl(sv[c], j + 4);
            float a5 = __shfl(wv[c], j + 5); int s5 = __shfl(sv[c], j + 5);
            float a6 = __shfl(wv[c], j + 6); int s6 = __shfl(sv[c], j + 6);
            float a7 = __shfl(wv[c], j + 7); int s7 = __shfl(sv[c], j + 7);
            uint2 u0 = xb[(size_t)s0 * 64];
            uint2 u1 = xb[(size_t)s1 * 64];
            uint2 u2 = xb[(size_t)s2 * 64];
            uint2 u3 = xb[(size_t)s3 * 64];
            uint2 u4 = xb[(size_t)s4 * 64];
            uint2 u5 = xb[(size_t)s5 * 64];
            uint2 u6 = xb[(size_t)s6 * 64];
            uint2 u7 = xb[(size_t)s7 * 64];
            acc.x += a0 * bl(u0.x); acc.y += a0 * bh(u0.x);
            acc.z += a0 * bl(u0.y); acc.w += a0 * bh(u0.y);
            acc.x += a1 * bl(u1.x); acc.y += a1 * bh(u1.x);
            acc.z += a1 * bl(u1.y); acc.w += a1 * bh(u1.y);
            acc.x += a2 * bl(u2.x); acc.y += a2 * bh(u2.x);
            acc.z += a2 * bl(u2.y); acc.w += a2 * bh(u2.y);
            acc.x += a3 * bl(u3.x); acc.y += a3 * bh(u3.x);
            acc.z += a3 * bl(u3.y); acc.w += a3 * bh(u3.y);
            acc.x += a4 * bl(u4.x); acc.y += a4 * bh(u4.x);
            acc.z += a4 * bl(u4.y); acc.w += a4 * bh(u4.y);
            acc.x += a5 * bl(u5.x); acc.y += a5 * bh(u5.x);
            acc.z += a5 * bl(u5.y); acc.w += a5 * bh(u5.y);
            acc.x += a6 * bl(u6.x); acc.y += a6 * bh(u6.x);
            acc.z += a6 * bl(u6.y); acc.w += a6 * bh(u6.y);
            acc.x += a7 * bl(u7.x); acc.y += a7 * bh(u7.x);
            acc.z += a7 * bl(u7.y); acc.w += a7 * bh(u7.y);
        }
        for (; j + 4 <= cnt; j += 4) {
            float a0 = __shfl(wv[c], j);     int s0 = __shfl(sv[c], j);
            float a1 = __shfl(wv[c], j + 1); int s1 = __shfl(sv[c], j + 1);
            float a2 = __shfl(wv[c], j + 2); int s2 = __shfl(sv[c], j + 2);
            float a3 = __shfl(wv[c], j + 3); int s3 = __shfl(sv[c], j + 3);
            uint2 u0 = xb[(size_t)s0 * 64];
            uint2 u1 = xb[(size_t)s1 * 64];
            uint2 u2 = xb[(size_t)s2 * 64];
            uint2 u3 = xb[(size_t)s3 * 64];
            acc.x += a0 * bl(u0.x); acc.y += a0 * bh(u0.x);
            acc.z += a0 * bl(u0.y); acc.w += a0 * bh(u0.y);
            acc.x += a1 * bl(u1.x); acc.y += a1 * bh(u1.x);
            acc.z += a1 * bl(u1.y); acc.w += a1 * bh(u1.y);
            acc.x += a2 * bl(u2.x); acc.y += a2 * bh(u2.x);
            acc.z += a2 * bl(u2.y); acc.w += a2 * bh(u2.y);
            acc.x += a3 * bl(u3.x); acc.y += a3 * bh(u3.x);
            acc.z += a3 * bl(u3.y); acc.w += a3 * bh(u3.y);
        }
        for (; j < cnt; ++j) {
            float a = __shfl(wv[c], j);
            int   s = __shfl(sv[c], j);
            uint2 u = xb[(size_t)s * 64];
            acc.x += a * bl(u.x); acc.y += a * bh(u.x);
            acc.z += a * bl(u.y); acc.w += a * bh(u.y);
        }
    }
    acc.x *= inv; acc.y *= inv; acc.z *= inv; acc.w *= inv;
    out4[(size_t)v * 64 + lane] = acc;
}

extern "C" void kernel_launch(void* const* d_in, const int* in_sizes, int n_in,
                              void* d_out, int out_size, void* d_ws, size_t ws_size,
                              hipStream_t stream) {
    const float* x   = (const float*)d_in[0];
    const int*   src = (const int*)d_in[1];
    const int*   dst = (const int*)d_in[2];
    const float* Wq  = (const float*)d_in[3];
    const float* bq  = (const float*)d_in[4];
    const float* Wk  = (const float*)d_in[5];
    const float* bk  = (const float*)d_in[6];
    float* out = (float*)d_out;

    int N = in_sizes[0] / D;
    int E = in_sizes[1];

    char* p = (char*)d_ws;
    auto alloc = [&](size_t bytes) {
        char* r = p;
        p += (bytes + 255) & ~(size_t)255;
        return r;
    };
    unsigned short* xh   = (unsigned short*)alloc((size_t)N * D * sizeof(unsigned short));
    unsigned short* wt_g = (unsigned short*)alloc(64 * 256 * sizeof(unsigned short));
    float* bias_g  = (float*)alloc(64 * sizeof(float));
    float* qp      = (float*)alloc((size_t)N * QS * sizeof(float));
    float* kp      = (float*)alloc((size_t)N * QS * sizeof(float));
    int*   cnt     = (int*)  alloc((size_t)(N + 4) * sizeof(int));
    int*   off     = (int*)  alloc((size_t)(N + 4) * sizeof(int));
    int*   cursor  = (int*)  alloc((size_t)(N + 4) * sizeof(int));
    int*   csr_src = (int*)  alloc((size_t)E * sizeof(int));
    int*   bsum    = (int*)  alloc(64 * sizeof(int));

    int prepgrid = (N > 16448 ? N : 16448);
    prep_kernel<<<(prepgrid + 255) / 256, 256, 0, stream>>>(
        Wq, bq, Wk, bk, wt_g, bias_g, cnt, N);
    int nqk = (N + 63) / 64;
    qk_kernel<<<nqk, 256, 0, stream>>>(x, wt_g, bias_g, (const int4*)dst, dst,
                                       xh, qp, kp, cnt, N, E);
    int n4 = (N + 3) / 4;
    int nblk = (n4 + 255) / 256;   // 49 for N=50000; must be <= 64
    scan_a_kernel<<<nblk, 256, 0, stream>>>((const int4*)cnt, bsum, n4);
    scan_c_kernel<<<nblk, 256, 0, stream>>>((const int4*)cnt, bsum, off + N,
                                            (int4*)off, (int4*)cursor, n4, nblk);
    int n4e = E / 4;
    scatter_kernel<<<(n4e + 255) / 256, 256, 0, stream>>>(
        (const int4*)src, (const int4*)dst, src, dst, cursor, csr_src, n4e, E);
    agg_kernel<<<(N + 3) / 4, 256, 0, stream>>>(
        (const uint2*)xh, qp, kp, off, csr_src, (float4*)out, N);
}